// Round 1
// baseline (993.834 us; speedup 1.0000x reference)
//
#include <hip/hip_runtime.h>
#include <cfloat>
#include <math.h>

#define BT 64
#define CHN 256
#define HH 56
#define WW 56
#define HW 3136          // 56*56
#define NPIX (BT * HW)   // 200704

// ---------------------------------------------------------------------------
// Kernel A: per-pixel inverse channel-L2 norm, fp64 (1/max(||x||,1e-12)).
// Memory bound: reads 205 MB coalesced, writes 1.6 MB to workspace.
// ---------------------------------------------------------------------------
__global__ __launch_bounds__(256) void norm_kernel(const float* __restrict__ x,
                                                   double* __restrict__ invn) {
    int p = blockIdx.x * 256 + threadIdx.x;
    if (p >= NPIX) return;
    int b = p / HW;
    int yx = p - b * HW;
    const float* xb = x + (size_t)b * (CHN * HW) + yx;
    double s = 0.0;
    #pragma unroll 8
    for (int c = 0; c < CHN; ++c) {
        float v = xb[(size_t)c * HW];
        s += (double)v * (double)v;
    }
    double n = sqrt(s);
    invn[p] = 1.0 / fmax(n, 1e-12);
}

// ---------------------------------------------------------------------------
// Kernel B: correlation volume (81 offsets) + argmax + collapsed softmax.
// WG = 192 threads = 3 waves. Tile = 16x16 pixels. Each wave: all 256 tile
// pixels (64 lanes x T=4 px in x), dy rows {0-2},{3-5},{6-8} -> 27 offsets,
// acc[27][4] fp32 in VGPRs. Channels staged 4 at a time through LDS.
// Raw dot accumulated; scaled by fp64 inv-norms in epilogue.
// ---------------------------------------------------------------------------
__global__ __launch_bounds__(192, 3) void corr_kernel(const float* __restrict__ x,
                                                      const double* __restrict__ invn,
                                                      float* __restrict__ out) {
    const int tile = blockIdx.x;   // 0..15
    const int b    = blockIdx.y;   // 0..63
    const int offs0 = (tile & 3);
    const int offs1 = (tile >> 2);
    // tile origins {0,16,32,40}: full coverage of 56 with overlap (idempotent writes)
    const int x0 = (offs0 < 3) ? offs0 * 16 : 40;
    const int y0 = (offs1 < 3) ? offs1 * 16 : 40;
    const int tid = threadIdx.x;

    float* outb = out + (size_t)b * 3 * HW;

    if ((b & 7) == 0) {
        // first frame of each segment: x_post == 0 -> r == 0 everywhere ->
        // conf = 0, p = 0 -> mot = 0 (exactly matches reference arithmetic)
        for (int i = tid; i < 256; i += 192) {
            int py = i >> 4, px = i & 15;
            int g = (y0 + py) * WW + (x0 + px);
            outb[g] = 0.f; outb[HW + g] = 0.f; outb[2 * HW + g] = 0.f;
        }
        return;
    }

    const int wave = tid / 64;
    const int lane = tid & 63;
    const int ty  = lane >> 2;   // 0..15 tile row
    const int tx4 = lane & 3;    // 0..3  -> pixels x-local 4*tx4 .. 4*tx4+3

    __shared__ float  xs[4 * 16 * 20];   // [ch][ty][20pad] current-frame tile
    __shared__ float  ps[4 * 24 * 36];   // [ch][row][36pad] prev-frame halo tile
    __shared__ double ivq[24 * 25];      // prev-frame inv-norms (halo), 0 if OOB
    __shared__ double ivp[16 * 16];      // current-frame inv-norms
    __shared__ float  red_v[3 * 256];
    __shared__ int    red_o[3 * 256];

    const float*  xcur    = x    + (size_t)b * (CHN * HW);
    const float*  xprv    = x    + (size_t)(b - 1) * (CHN * HW);
    const double* inv_cur = invn + (size_t)b * HW;
    const double* inv_prv = invn + (size_t)(b - 1) * HW;

    // stage inverse norms (once)
    for (int i = tid; i < 576; i += 192) {
        int row = i / 24, col = i % 24;
        int gy = y0 - 4 + row, gx = x0 - 4 + col;
        double v = 0.0;
        if (gy >= 0 && gy < HH && gx >= 0 && gx < WW) v = inv_prv[gy * WW + gx];
        ivq[row * 25 + col] = v;
    }
    for (int i = tid; i < 256; i += 192) {
        int py = i >> 4, px = i & 15;
        ivp[i] = inv_cur[(y0 + py) * WW + (x0 + px)];
    }

    // precompute staging descriptors (loop-invariant)
    int  xp_l[3], xp_g[3];
    bool xp_v[3];
    #pragma unroll
    for (int k = 0; k < 3; ++k) {
        int i = tid + k * 192;                 // 0..575
        int ch = i / 144, rem = i % 144;
        int row = rem / 6, c4 = rem % 6;
        int gy = y0 - 4 + row, gx = x0 - 4 + 4 * c4;
        xp_v[k] = (gy >= 0 && gy < HH && gx >= 0 && gx < WW);
        xp_l[k] = (ch * 24 + row) * 36 + 4 * c4;
        xp_g[k] = ch * HW + (xp_v[k] ? (gy * WW + gx) : 0);
    }
    int xt_l[2], xt_g[2];
    #pragma unroll
    for (int k = 0; k < 2; ++k) {
        int i = tid + k * 192;                 // 0..255 (k=1 valid iff tid<64)
        int ii = (i < 256) ? i : 0;
        int ch = ii >> 6, rem = ii & 63;
        int sy = rem >> 2, sx = rem & 3;
        xt_l[k] = (ch * 16 + sy) * 20 + 4 * sx;
        xt_g[k] = ch * HW + (y0 + sy) * WW + x0 + 4 * sx;
    }

    float acc[27][4];
    #pragma unroll
    for (int j = 0; j < 27; ++j) {
        #pragma unroll
        for (int t = 0; t < 4; ++t) acc[j][t] = 0.f;
    }

    const int dy0 = wave * 3;                      // dy rows {0-2},{3-5},{6-8}
    const float* xb = &xs[ty * 20 + 4 * tx4];
    const float* pb = &ps[(ty + dy0) * 36 + 4 * tx4];

    for (int cc = 0; cc < 64; ++cc) {
        const size_t cbase = (size_t)(cc * 4) * HW;
        __syncthreads();  // previous compute done before overwriting LDS
        // stage x tile: 4ch x 16 x 16
        {
            float4 v = *(const float4*)(xcur + cbase + xt_g[0]);
            *(float4*)&xs[xt_l[0]] = v;
            if (tid < 64) {
                float4 v1 = *(const float4*)(xcur + cbase + xt_g[1]);
                *(float4*)&xs[xt_l[1]] = v1;
            }
        }
        // stage xp halo tile: 4ch x 24 x 24 (zeros outside image)
        #pragma unroll
        for (int k = 0; k < 3; ++k) {
            float4 v = make_float4(0.f, 0.f, 0.f, 0.f);
            if (xp_v[k]) v = *(const float4*)(xprv + cbase + xp_g[k]);
            *(float4*)&ps[xp_l[k]] = v;
        }
        __syncthreads();
        // accumulate: per channel, per dy row, sliding 12-float window
        #pragma unroll
        for (int ch = 0; ch < 4; ++ch) {
            float4 xq = *(const float4*)(xb + ch * 320);
            #pragma unroll
            for (int r = 0; r < 3; ++r) {
                float4 w0 = *(const float4*)(pb + ch * 864 + r * 36);
                float4 w1 = *(const float4*)(pb + ch * 864 + r * 36 + 4);
                float4 w2 = *(const float4*)(pb + ch * 864 + r * 36 + 8);
                float win[12];
                win[0] = w0.x; win[1] = w0.y; win[2]  = w0.z; win[3]  = w0.w;
                win[4] = w1.x; win[5] = w1.y; win[6]  = w1.z; win[7]  = w1.w;
                win[8] = w2.x; win[9] = w2.y; win[10] = w2.z; win[11] = w2.w;
                #pragma unroll
                for (int dx = 0; dx < 9; ++dx) {
                    int j = r * 9 + dx;
                    acc[j][0] = fmaf(xq.x, win[dx + 0], acc[j][0]);
                    acc[j][1] = fmaf(xq.y, win[dx + 1], acc[j][1]);
                    acc[j][2] = fmaf(xq.z, win[dx + 2], acc[j][2]);
                    acc[j][3] = fmaf(xq.w, win[dx + 3], acc[j][3]);
                }
            }
        }
    }

    // epilogue: per-wave argmax over its 27 offsets (flat order -> first-max tie-break)
    double ip[4];
    #pragma unroll
    for (int t = 0; t < 4; ++t) ip[t] = ivp[ty * 16 + 4 * tx4 + t];
    float bv[4] = { -FLT_MAX, -FLT_MAX, -FLT_MAX, -FLT_MAX };
    int   bo[4] = { 0, 0, 0, 0 };
    #pragma unroll
    for (int r = 0; r < 3; ++r) {
        #pragma unroll
        for (int dx = 0; dx < 9; ++dx) {
            int j = r * 9 + dx;
            #pragma unroll
            for (int t = 0; t < 4; ++t) {
                double q = ivq[(ty + dy0 + r) * 25 + 4 * tx4 + t + dx];
                float rv = (float)((double)acc[j][t] * ip[t] * q);
                if (rv > bv[t]) { bv[t] = rv; bo[t] = 27 * wave + j; }
            }
        }
    }
    #pragma unroll
    for (int t = 0; t < 4; ++t) {
        int p = ty * 16 + 4 * tx4 + t;
        red_v[wave * 256 + p] = bv[t];
        red_o[wave * 256 + p] = bo[t];
    }
    __syncthreads();

    // cross-wave combine (ascending wave = ascending flat offset; strict >)
    for (int p = tid; p < 256; p += 192) {
        float v = red_v[p]; int o = red_o[p];
        float v1 = red_v[256 + p];
        if (v1 > v) { v = v1; o = red_o[256 + p]; }
        float v2 = red_v[512 + p];
        if (v2 > v) { v = v2; o = red_o[512 + p]; }
        float h_idx = (float)(o / 9) - 4.f;
        float v_idx = (float)(o % 9) - 4.f;
        // gaussian(sigma=0.1) kills all non-argmax cells below fp32 resolution:
        // h_cord = h_idx * R/(R+1e-12), R = BETA*r_max (== h_idx exactly for normal R)
        float R  = 10.f * v;
        float pc = R / (R + 1e-12f);
        int py = p >> 4, px = p & 15;
        int g = (y0 + py) * WW + (x0 + px);
        outb[g]          = h_idx * pc;
        outb[HW + g]     = v_idx * pc;
        outb[2 * HW + g] = v;
    }
}

extern "C" void kernel_launch(void* const* d_in, const int* in_sizes, int n_in,
                              void* d_out, int out_size, void* d_ws, size_t ws_size,
                              hipStream_t stream) {
    const float* x = (const float*)d_in[0];
    float* out = (float*)d_out;
    double* invn = (double*)d_ws;   // 200704 doubles = 1.6 MB

    hipLaunchKernelGGL(norm_kernel, dim3((NPIX + 255) / 256), dim3(256), 0, stream,
                       x, invn);
    hipLaunchKernelGGL(corr_kernel, dim3(16, 64), dim3(192), 0, stream,
                       x, invn, out);
}

// Round 2
// 988.713 us; speedup vs baseline: 1.0052x; 1.0052x over previous
//
#include <hip/hip_runtime.h>
#include <cfloat>
#include <math.h>

#define BT 64
#define CHN 256
#define HH 56
#define WW 56
#define HW 3136          // 56*56
#define NPIX (BT * HW)   // 200704

// ---------------------------------------------------------------------------
// Kernel A: per-pixel inverse channel-L2 norm (fp64 result).
// 256 threads = 64 pixels x 4 channel-quarters -> high MLP, 100% occupancy,
// coalesced 256B/wave loads. 3136 blocks.
// ---------------------------------------------------------------------------
__global__ __launch_bounds__(256) void norm_kernel(const float* __restrict__ x,
                                                   double* __restrict__ invn) {
    __shared__ double part[4][64];
    const int px = threadIdx.x & 63;
    const int q  = threadIdx.x >> 6;
    const int p0 = blockIdx.x * 64;
    const int b  = blockIdx.x / 49;              // HW = 49 * 64, blocks never cross b
    const int yx = p0 - b * HW + px;
    const float* xb = x + (size_t)b * (CHN * HW) + (size_t)(q * 64) * HW + yx;
    double s = 0.0;
    #pragma unroll 16
    for (int c = 0; c < 64; ++c) {
        float v = xb[(size_t)c * HW];
        s += (double)v * (double)v;
    }
    part[q][px] = s;
    __syncthreads();
    if (threadIdx.x < 64) {
        double t = part[0][px] + part[1][px] + part[2][px] + part[3][px];
        invn[p0 + px] = 1.0 / fmax(sqrt(t), 1e-12);
    }
}

// ---------------------------------------------------------------------------
// Kernel B: correlation volume (81 offsets) + argmax + collapsed softmax.
// Block = 576 threads = 9 waves; wave w owns dy row w (9 dx offsets).
// Each lane: T=4 contiguous x-pixels -> acc[9][4] = 36 VGPRs (NO SPILL —
// round 1's acc[27][4]=108 spilled to scratch: 1.37 GB scratch writes).
// Channels staged 4 at a time through LDS; argmax merged across waves via
// packed u64 (sortable float key << 32 | (80 - offset)) + LDS atomicMax,
// which preserves the reference's first-max tie-break exactly.
// ---------------------------------------------------------------------------
__global__ __launch_bounds__(576, 6) void corr_kernel(const float* __restrict__ x,
                                                      const double* __restrict__ invn,
                                                      float* __restrict__ out) {
    const int tile = blockIdx.x;   // 0..15
    const int b    = blockIdx.y;   // 0..63
    const int offs0 = (tile & 3);
    const int offs1 = (tile >> 2);
    // tile origins {0,16,32,40}: full coverage of 56 with overlap (idempotent writes)
    const int x0 = (offs0 < 3) ? offs0 * 16 : 40;
    const int y0 = (offs1 < 3) ? offs1 * 16 : 40;
    const int tid = threadIdx.x;

    float* outb = out + (size_t)b * 3 * HW;

    if ((b & 7) == 0) {
        // first frame of each segment: x_post == 0 -> r == 0 -> mot = 0, conf = 0
        if (tid < 256) {
            int py = tid >> 4, px = tid & 15;
            int g = (y0 + py) * WW + (x0 + px);
            outb[g] = 0.f; outb[HW + g] = 0.f; outb[2 * HW + g] = 0.f;
        }
        return;
    }

    const int wave = tid >> 6;     // 0..8 == dy row
    const int lane = tid & 63;
    const int ty  = lane >> 2;     // 0..15 tile row
    const int tx4 = lane & 3;      // pixel group: x-local 4*tx4 .. 4*tx4+3

    __shared__ float  xs[4 * 16 * 20];          // [ch][ty][20pad] current tile
    __shared__ float  ps[4 * 24 * 36];          // [ch][row][36pad] prev halo
    __shared__ double ivq[24 * 25];             // prev inv-norms (halo), 0 if OOB
    __shared__ double ivp[256];                 // current inv-norms
    __shared__ unsigned long long red[256];     // packed argmax per pixel

    const float*  xcur    = x    + (size_t)b * (CHN * HW);
    const float*  xprv    = x    + (size_t)(b - 1) * (CHN * HW);
    const double* inv_cur = invn + (size_t)b * HW;
    const double* inv_prv = invn + (size_t)(b - 1) * HW;

    // stage inverse norms + init reduction slots (576 = 24*24 exactly)
    {
        int row = tid / 24, col = tid - row * 24;
        int gy = y0 - 4 + row, gx = x0 - 4 + col;
        double v = 0.0;
        if (gy >= 0 && gy < HH && gx >= 0 && gx < WW) v = inv_prv[gy * WW + gx];
        ivq[row * 25 + col] = v;
    }
    if (tid < 256) {
        ivp[tid] = inv_cur[(y0 + (tid >> 4)) * WW + x0 + (tid & 15)];
        red[tid] = 0ULL;
    }

    // staging descriptors (one float4 per thread for ps: 4ch*24rows*6groups = 576)
    int ch_s  = tid / 144;
    int rem_s = tid - ch_s * 144;
    int row_s = rem_s / 6;
    int c4    = rem_s - row_s * 6;
    int gy_s  = y0 - 4 + row_s;
    int gx_s  = x0 - 4 + 4 * c4;
    const bool pv = (gy_s >= 0 && gy_s < HH && gx_s >= 0 && gx_s < WW); // never straddles
    const int    ps_l = (ch_s * 24 + row_s) * 36 + 4 * c4;
    const size_t ps_g = (size_t)ch_s * HW + (pv ? (gy_s * WW + gx_s) : 0);
    int xs_l = 0; size_t xs_g = 0;
    if (tid < 256) {               // 4ch * 16rows * 4groups = 256
        int chx = tid >> 6, r2 = tid & 63, sy = r2 >> 2, sx = r2 & 3;
        xs_l = (chx * 16 + sy) * 20 + 4 * sx;
        xs_g = (size_t)chx * HW + (size_t)(y0 + sy) * WW + x0 + 4 * sx;
    }

    float acc[9][4];
    #pragma unroll
    for (int j = 0; j < 9; ++j)
        #pragma unroll
        for (int t = 0; t < 4; ++t) acc[j][t] = 0.f;

    const float* xb = &xs[ty * 20 + 4 * tx4];
    const float* pb = &ps[(ty + wave) * 36 + 4 * tx4];

    for (int cc = 0; cc < 64; ++cc) {
        const size_t cb = (size_t)(cc * 4) * HW;
        __syncthreads();  // previous compute done before overwriting LDS
        {
            float4 v = make_float4(0.f, 0.f, 0.f, 0.f);
            if (pv) v = *(const float4*)(xprv + cb + ps_g);
            *(float4*)&ps[ps_l] = v;
        }
        if (tid < 256) {
            *(float4*)&xs[xs_l] = *(const float4*)(xcur + cb + xs_g);
        }
        __syncthreads();
        #pragma unroll
        for (int ch = 0; ch < 4; ++ch) {
            float4 xq = *(const float4*)(xb + ch * 320);
            float4 w0 = *(const float4*)(pb + ch * 864);
            float4 w1 = *(const float4*)(pb + ch * 864 + 4);
            float4 w2 = *(const float4*)(pb + ch * 864 + 8);
            float win[12] = { w0.x, w0.y, w0.z, w0.w,
                              w1.x, w1.y, w1.z, w1.w,
                              w2.x, w2.y, w2.z, w2.w };
            #pragma unroll
            for (int dx = 0; dx < 9; ++dx) {
                acc[dx][0] = fmaf(xq.x, win[dx + 0], acc[dx][0]);
                acc[dx][1] = fmaf(xq.y, win[dx + 1], acc[dx][1]);
                acc[dx][2] = fmaf(xq.z, win[dx + 2], acc[dx][2]);
                acc[dx][3] = fmaf(xq.w, win[dx + 3], acc[dx][3]);
            }
        }
    }

    // epilogue: local argmax over this wave's 9 offsets, packed-u64 merge
    const int px0 = ty * 16 + 4 * tx4;
    double ip[4];
    #pragma unroll
    for (int t = 0; t < 4; ++t) ip[t] = ivp[px0 + t];
    unsigned long long best[4] = { 0ULL, 0ULL, 0ULL, 0ULL };
    #pragma unroll
    for (int dx = 0; dx < 9; ++dx) {
        #pragma unroll
        for (int t = 0; t < 4; ++t) {
            double qv = ivq[(ty + wave) * 25 + 4 * tx4 + t + dx];
            float rv = (float)((double)acc[dx][t] * ip[t] * qv);
            unsigned int bits = __float_as_uint(rv);
            unsigned int key = (bits & 0x80000000u) ? ~bits : (bits | 0x80000000u);
            unsigned long long pk =
                ((unsigned long long)key << 32) | (unsigned int)(80 - (wave * 9 + dx));
            if (pk > best[t]) best[t] = pk;   // ascending dx + strict > == first-max
        }
    }
    #pragma unroll
    for (int t = 0; t < 4; ++t) atomicMax(&red[px0 + t], best[t]);
    __syncthreads();

    if (tid < 256) {
        unsigned long long pk = red[tid];
        int o = 80 - (int)(pk & 0xffffffffu);
        unsigned int key  = (unsigned int)(pk >> 32);
        unsigned int bits = (key & 0x80000000u) ? (key ^ 0x80000000u) : ~key;
        float v = __uint_as_float(bits);
        float h_idx = (float)(o / 9) - 4.f;
        float v_idx = (float)(o - (o / 9) * 9) - 4.f;
        // gaussian(sigma=0.1) zeroes all non-argmax cells below fp32 resolution:
        // h_cord = h_idx * R/(R+1e-12), R = BETA * r_max
        float R  = 10.f * v;
        float pc = R / (R + 1e-12f);
        int py = tid >> 4, pxl = tid & 15;
        int g = (y0 + py) * WW + (x0 + pxl);
        outb[g]          = h_idx * pc;
        outb[HW + g]     = v_idx * pc;
        outb[2 * HW + g] = v;
    }
}

extern "C" void kernel_launch(void* const* d_in, const int* in_sizes, int n_in,
                              void* d_out, int out_size, void* d_ws, size_t ws_size,
                              hipStream_t stream) {
    const float* x = (const float*)d_in[0];
    float* out = (float*)d_out;
    double* invn = (double*)d_ws;   // 200704 doubles = 1.6 MB

    hipLaunchKernelGGL(norm_kernel, dim3(NPIX / 64), dim3(256), 0, stream,
                       x, invn);
    hipLaunchKernelGGL(corr_kernel, dim3(16, 64), dim3(576), 0, stream,
                       x, invn, out);
}